// Round 10
// baseline (42445.020 us; speedup 1.0000x reference)
//
#include <hip/hip_runtime.h>
#include <math.h>

static constexpr int Tt   = 512;
static constexpr int INF  = 256;
static constexpr int Hf   = 512;
static constexpr int OUTF = 10;
static constexpr int NBLK = 256;   // 128 layer-0 blocks + 128 layer-1 blocks
static constexpr int NTHR = 1024;  // 16 waves
static constexpr int SGLOB = Tt + 2;
static constexpr unsigned SMEM_BYTES = 98304 + 49152 + 4096; // weights + pb + locals

__device__ __forceinline__ float sigmoidf_(float x) {
    return 1.0f / (1.0f + __expf(-x));
}
__device__ __forceinline__ float tanhf_(float x) {
    float e = __expf(-2.0f * fabsf(x));
    float r = (1.0f - e) / (1.0f + e);
    return copysignf(r, x);
}

// 4-byte agent-scope (sc1 / LLC-served) access: r3/r7-proven path.
__device__ __forceinline__ float ldc(const float* p) {
    return __hip_atomic_load(const_cast<float*>(p), __ATOMIC_RELAXED, __HIP_MEMORY_SCOPE_AGENT);
}
__device__ __forceinline__ void stc(float* p, float v) {
    __hip_atomic_store(p, v, __ATOMIC_RELAXED, __HIP_MEMORY_SCOPE_AGENT);
}

// Grid barrier via ONE LLC-resident atomic counter.
// arrive: drain stores -> block barrier -> +1 (memory-side atomic).
// wait:   ONE thread polls (s_sleep backoff) -> block barrier.
__device__ __forceinline__ void arrive_(unsigned* ctr) {
    asm volatile("s_waitcnt vmcnt(0)" ::: "memory");
    __syncthreads();
    if (threadIdx.x == 0)
        __hip_atomic_fetch_add(ctr, 1u, __ATOMIC_RELAXED, __HIP_MEMORY_SCOPE_AGENT);
}
__device__ __forceinline__ void wait_(unsigned* ctr, unsigned target) {
    if (threadIdx.x == 0) {
        while (__hip_atomic_load(ctr, __ATOMIC_RELAXED, __HIP_MEMORY_SCOPE_AGENT) < target)
            __builtin_amdgcn_s_sleep(8);
    }
    __syncthreads();
}

// x (B,T,IN) -> xT (T,IN,B)
__global__ __launch_bounds__(256) void transpose_x_k(const float* __restrict__ x,
                                                     float* __restrict__ xT) {
    __shared__ float tile[64][65];
    int t  = blockIdx.x;
    int k0 = blockIdx.y * 64;
    int tid = threadIdx.x;
#pragma unroll
    for (int i = 0; i < 16; ++i) {
        int idx = i * 256 + tid;
        int bb = idx >> 6, kk = idx & 63;
        tile[bb][kk] = x[(size_t)bb * Tt * INF + (size_t)t * INF + k0 + kk];
    }
    __syncthreads();
#pragma unroll
    for (int i = 0; i < 16; ++i) {
        int idx = i * 256 + tid;
        int kk = idx >> 6, bb = idx & 63;
        xT[(size_t)t * INF * 64 + (size_t)(k0 + kk) * 64 + bb] = tile[bb][kk];
    }
}

#define FMA4(a, w, v) { (a).x = fmaf((w).x, (v), (a).x); (a).y = fmaf((w).y, (v), (a).y); \
                        (a).z = fmaf((w).z, (v), (a).z); (a).w = fmaf((w).w, (v), (a).w); }

template<bool SC>
__device__ __forceinline__ float ldx(const float* p) { return SC ? ldc(p) : *p; }

// x-projection windows: prefetch x slice to regs, LDS weight broadcast.
template<int L16, bool SC>
__device__ __forceinline__ void xw2(const float* xs, int lane, int wv,
                                    const float4* w0, const float4* w1,
                                    float4& a0, float4& a1) {
    const int kb = wv * L16;
    float xv[L16];
#pragma unroll
    for (int i = 0; i < L16; ++i) xv[i] = ldx<SC>(xs + (size_t)(kb + i) * 64 + lane);
#pragma unroll
    for (int i = 0; i < L16; ++i) {
        float4 w = w0[kb + i]; FMA4(a0, w, xv[i]);
        w = w1[kb + i];        FMA4(a1, w, xv[i]);
    }
}
template<int L16, bool SC>
__device__ __forceinline__ void xw3(const float* xs, int lane, int wv,
                                    const float4* w0, const float4* w1, const float4* w2,
                                    float4& a0, float4& a1, float4& a2) {
    const int kb = wv * L16;
    float xv[L16];
#pragma unroll
    for (int i = 0; i < L16; ++i) xv[i] = ldx<SC>(xs + (size_t)(kb + i) * 64 + lane);
#pragma unroll
    for (int i = 0; i < L16; ++i) {
        float4 w = w0[kb + i]; FMA4(a0, w, xv[i]);
        w = w1[kb + i];        FMA4(a1, w, xv[i]);
        w = w2[kb + i];        FMA4(a2, w, xv[i]);
    }
}

// One layer's persistent loop (inlined per role; LIN compile-time).
template<int LIN, bool XSC, bool WY>
__device__ __forceinline__ void run_layer(
    const float* __restrict__ xsrc, float* y0,
    float* r0, float* r1, float* h0, float* h1, float* rhB, float* hgB,
    const float* __restrict__ Win, const float* __restrict__ Wres,
    const float* __restrict__ Wz, const float* __restrict__ bz,
    const float* __restrict__ Wr, const float* __restrict__ br,
    const float* __restrict__ Wc, const float* __restrict__ bc,
    const float* __restrict__ Wg, const float* __restrict__ bg,
    const float* __restrict__ Wp, const float* __restrict__ bp,
    unsigned* ctr, int c0, int tshift)
{
    constexpr int L16 = LIN / 16;
    extern __shared__ char smem[];
    float4* wRESx = (float4*)smem;   // LIN
    float4* wRESs = wRESx + LIN;     // 512
    float4* wZx   = wRESs + 512;     // LIN
    float4* wZs   = wZx + LIN;       // 512
    float4* wRx   = wZs + 512;       // LIN
    float4* wRs   = wRx + LIN;       // 512
    float4* wCx   = wRs + 512;       // LIN
    float4* wCs   = wCx + LIN;       // 512
    float4* wGx   = wCs + 512;       // LIN
    float4* wGh   = wGx + LIN;       // 512
    float4* wGr   = wGh + 512;       // 512
    float4* wP    = wGr + 512;       // 512
    float* pb  = (float*)(smem + (size_t)(5 * LIN + 3584) * 16); // [3][4][16][64]
    float* lz  = pb + 12288;
    float* lp  = lz + 256;
    float* lgg = lp + 256;
    float* lhg = lgg + 256;

    const int tid  = threadIdx.x;
    const int lane = tid & 63;
    const int wv   = tid >> 6;

    // ---- stage this block's 4 columns of every matrix into LDS
    for (int k = tid; k < LIN; k += NTHR) {
        wRESx[k] = *(const float4*)&Win[(size_t)k * 512 + c0];
        wZx[k]   = *(const float4*)&Wz[(size_t)k * 512 + c0];
        wRx[k]   = *(const float4*)&Wr[(size_t)k * 512 + c0];
        wCx[k]   = *(const float4*)&Wc[(size_t)k * 512 + c0];
        wGx[k]   = *(const float4*)&Wg[(size_t)k * 512 + c0];
    }
    for (int k = tid; k < 512; k += NTHR) {
        wRESs[k] = *(const float4*)&Wres[(size_t)k * 512 + c0];
        wZs[k]   = *(const float4*)&Wz[(size_t)(LIN + k) * 512 + c0];
        wRs[k]   = *(const float4*)&Wr[(size_t)(LIN + k) * 512 + c0];
        wCs[k]   = *(const float4*)&Wc[(size_t)(LIN + k) * 512 + c0];
        wGh[k]   = *(const float4*)&Wg[(size_t)(LIN + k) * 512 + c0];
        wGr[k]   = *(const float4*)&Wg[(size_t)(LIN + 512 + k) * 512 + c0];
        wP[k]    = *(const float4*)&Wp[(size_t)k * 512 + c0];
    }
    __syncthreads();

    // reduce-thread identity
    const int m    = tid >> 8;
    const int rrem = tid & 255;
    const int cdx  = rrem >> 6;
    const int rbb  = rrem & 63;
    const int cab  = c0 + cdx;
    const int gi   = cab * 64 + rbb;
    float bzr = 0, brr = 0, bcr = 0, bpr = 0, bgr = 0;
    if (tid < 768) {
        bzr = bz[cab]; brr = br[cab]; bcr = bc[cab]; bpr = bp[cab]; bgr = bg[cab];
    }

#define PB_WRITE(mm, v) { \
    pb[(((mm)*4+0)*16+wv)*64+lane] = (v).x; \
    pb[(((mm)*4+1)*16+wv)*64+lane] = (v).y; \
    pb[(((mm)*4+2)*16+wv)*64+lane] = (v).z; \
    pb[(((mm)*4+3)*16+wv)*64+lane] = (v).w; }

    unsigned ph = 0;
    const float4 z4 = {0.f, 0.f, 0.f, 0.f};
    float4 cRES = z4, cZ = z4, cR = z4, cX = z4, cG = z4;
    const int ks = wv * 32;

    // prologue: layer-0 carries for t=0
    if (tshift == 0)
        xw3<L16, XSC>(xsrc, lane, wv, wRESx, wZx, wRx, cRES, cZ, cR);

    for (int s = 0; s < SGLOB; ++s) {
        const int t = s - tshift;
        const bool act = (t >= 0) && (t < Tt);
        const bool wn  = (t + 1 >= 0) && (t + 1 < Tt);
        float* rc = (t & 1) ? r1 : r0;
        float* rn = (t & 1) ? r0 : r1;
        float* hc = (t & 1) ? h1 : h0;
        float* hn = (t & 1) ? h0 : h1;
        const float* xs_t = xsrc + (size_t)(act ? t : 0) * LIN * 64;
        const float* xs_n = xsrc + (size_t)(wn ? (t + 1) : 0) * LIN * 64;

        // ================= phase A: r_new, z, rh =================
        wait_(ctr, ph * NBLK);
        if (act) {
            float ownR = 0.f, ownH = 0.f;
            if (tid < 768) { if (m == 0) ownR = ldc(rc + gi); else if (m == 2) ownH = ldc(hc + gi); }
            float rv[32], hv[32];
#pragma unroll
            for (int i = 0; i < 32; ++i) rv[i] = ldc(rc + (size_t)(ks + i) * 64 + lane);
#pragma unroll
            for (int i = 0; i < 32; ++i) hv[i] = ldc(hc + (size_t)(ks + i) * 64 + lane);
            float4 aRES = cRES, aZ = cZ, aR = cR;
#pragma unroll
            for (int i = 0; i < 32; ++i) { float4 w = wRESs[ks + i]; FMA4(aRES, w, rv[i]); }
#pragma unroll
            for (int i = 0; i < 32; ++i) {
                float4 w = wZs[ks + i]; FMA4(aZ, w, hv[i]);
                w = wRs[ks + i];        FMA4(aR, w, hv[i]);
            }
            PB_WRITE(0, aRES); PB_WRITE(1, aZ); PB_WRITE(2, aR);
            __syncthreads();
            if (tid < 768) {
                float sa = 0.f;
#pragma unroll
                for (int w = 0; w < 16; ++w) sa += pb[((m * 4 + cdx) * 16 + w) * 64 + rbb];
                if (m == 0)      stc(rn + gi, 0.7f * ownR + 0.3f * tanhf_(sa));
                else if (m == 1) lz[rrem] = sigmoidf_(sa + bzr);
                else             stc(rhB + gi, sigmoidf_(sa + brr) * ownH);
            }
        }
        arrive_(ctr); ++ph;
        if (act) { cX = z4; cG = z4; xw2<L16, XSC>(xs_t, lane, wv, wCx, wGx, cX, cG); }
        wait_(ctr, ph * NBLK);

        // ================= phase B: h_gru, p, gg =================
        if (act) {
            float ownH = 0.f;
            if (tid < 768 && m == 0) ownH = ldc(hc + gi);
            float rnv[32], rhv[32];
#pragma unroll
            for (int i = 0; i < 32; ++i) rnv[i] = ldc(rn + (size_t)(ks + i) * 64 + lane);
#pragma unroll
            for (int i = 0; i < 32; ++i) rhv[i] = ldc(rhB + (size_t)(ks + i) * 64 + lane);
            float4 aC = cX, aP = z4, aG = cG;
#pragma unroll
            for (int i = 0; i < 32; ++i) {
                float4 w = wP[ks + i];  FMA4(aP, w, rnv[i]);
                w = wGr[ks + i];        FMA4(aG, w, rnv[i]);
            }
#pragma unroll
            for (int i = 0; i < 32; ++i) { float4 w = wCs[ks + i]; FMA4(aC, w, rhv[i]); }
            PB_WRITE(0, aC); PB_WRITE(1, aP); PB_WRITE(2, aG);
            __syncthreads();
            if (tid < 768) {
                float sa = 0.f;
#pragma unroll
                for (int w = 0; w < 16; ++w) sa += pb[((m * 4 + cdx) * 16 + w) * 64 + rbb];
                if (m == 0) {
                    float cand = tanhf_(sa + bcr);
                    float zv = lz[rrem];
                    float hg = (1.f - zv) * ownH + zv * cand;
                    stc(hgB + gi, hg);
                    lhg[rrem] = hg;
                } else if (m == 1) {
                    lp[rrem] = tanhf_(sa + bpr);
                } else {
                    lgg[rrem] = sa;
                }
            }
        }
        arrive_(ctr); ++ph;
        if (wn) { cRES = z4; cZ = z4; cR = z4;
                  xw3<L16, XSC>(xs_n, lane, wv, wRESx, wZx, wRx, cRES, cZ, cR); }
        wait_(ctr, ph * NBLK);

        // ================= phase C: g, h_new =================
        if (act) {
            float hgv[32];
#pragma unroll
            for (int i = 0; i < 32; ++i) hgv[i] = ldc(hgB + (size_t)(ks + i) * 64 + lane);
            float4 aGh = z4;
#pragma unroll
            for (int i = 0; i < 32; ++i) { float4 w = wGh[ks + i]; FMA4(aGh, w, hgv[i]); }
            PB_WRITE(0, aGh);
            __syncthreads();
            if (tid < 256) {
                float sa = 0.f;
#pragma unroll
                for (int w = 0; w < 16; ++w) sa += pb[((cdx) * 16 + w) * 64 + rbb];
                float g = sigmoidf_(sa + lgg[rrem] + bgr);
                float hnv = (1.f - g) * lhg[rrem] + g * lp[rrem];
                stc(hn + gi, hnv);
                if (WY) stc(y0 + (size_t)t * (Hf * 64) + gi, hnv);
            }
        }
        arrive_(ctr); ++ph;
    }
#undef PB_WRITE
}

struct KParams {
    const float* xT0;
    float* y0;
    const float *Win0,*Wres0,*Wz0,*bz0,*Wr0,*br0,*Wc0,*bc0,*Wg0,*bg0,*Wp0,*bp0;
    const float *Win1,*Wres1,*Wz1,*bz1,*Wr1,*br1,*Wc1,*bc1,*Wg1,*bg1,*Wp1,*bp1;
    float *r00,*r01,*h00,*h01,*rh0,*hg0;
    float *r10,*r11,*h10,*h11,*rh1,*hg1;
    unsigned* ctr;
};

// Dual-layer persistent kernel. Blocks 0-127: layer0 (t=s), 128-255: layer1 (t=s-2).
__global__ __launch_bounds__(NTHR) void esn_dual_k(KParams P)
{
    const int bid = blockIdx.x;
    const int c0  = (bid & 127) * 4;
    if (bid < 128) {
        run_layer<INF, false, true>(P.xT0, P.y0,
            P.r00, P.r01, P.h00, P.h01, P.rh0, P.hg0,
            P.Win0, P.Wres0, P.Wz0, P.bz0, P.Wr0, P.br0,
            P.Wc0, P.bc0, P.Wg0, P.bg0, P.Wp0, P.bp0,
            P.ctr, c0, 0);
    } else {
        run_layer<Hf, true, false>(P.y0, nullptr,
            P.r10, P.r11, P.h10, P.h11, P.rh1, P.hg1,
            P.Win1, P.Wres1, P.Wz1, P.bz1, P.Wr1, P.br1,
            P.Wc1, P.bc1, P.Wg1, P.bg1, P.Wp1, P.bp1,
            P.ctr, c0, 2);
    }
}

// Head: hid = relu(last@Wo1 + bo1). hlast layout [512 k][64 b].
__global__ __launch_bounds__(256) void head1_k(const float* __restrict__ hlast,
                                               const float* __restrict__ Wo1,
                                               const float* __restrict__ bo1,
                                               float* __restrict__ hidT) {
    int tid = threadIdx.x;
    int b = tid & 63, jg = tid >> 6;
    int j0 = blockIdx.x * 16 + jg * 4;
    float acc[4] = {0.f, 0.f, 0.f, 0.f};
    const float* ap = hlast + b;
    const float* wp = Wo1 + j0;
#pragma unroll 4
    for (int k = 0; k < Hf; ++k) {
        float xv = ap[k * 64];
        const float4 w = *reinterpret_cast<const float4*>(wp + k * 512);
        acc[0] = fmaf(w.x, xv, acc[0]);
        acc[1] = fmaf(w.y, xv, acc[1]);
        acc[2] = fmaf(w.z, xv, acc[2]);
        acc[3] = fmaf(w.w, xv, acc[3]);
    }
#pragma unroll
    for (int jj = 0; jj < 4; ++jj) {
        int j = j0 + jj;
        hidT[j * 64 + b] = fmaxf(acc[jj] + bo1[j], 0.f);
    }
}

__global__ __launch_bounds__(640) void head2_k(const float* __restrict__ hidT,
                                               const float* __restrict__ Wo2,
                                               const float* __restrict__ bo2,
                                               float* __restrict__ out) {
    int tid = threadIdx.x;
    if (tid >= 64 * OUTF) return;
    int b = tid / OUTF, o = tid % OUTF;
    float acc = 0.f;
    for (int k = 0; k < Hf; ++k)
        acc = fmaf(hidT[k * 64 + b], Wo2[k * OUTF + o], acc);
    out[tid] = acc + bo2[o];
}

extern "C" void kernel_launch(void* const* d_in, const int* in_sizes, int n_in,
                              void* d_out, int out_size, void* d_ws, size_t ws_size,
                              hipStream_t stream) {
    const float* x = (const float*)d_in[0];
    const float* W[2][12];
    int idx = 1;
    for (int li = 0; li < 2; ++li)
        for (int j = 0; j < 12; ++j) W[li][j] = (const float*)d_in[idx++];
    const float* Wo1 = (const float*)d_in[idx++];
    const float* bo1 = (const float*)d_in[idx++];
    const float* Wo2 = (const float*)d_in[idx++];
    const float* bo2 = (const float*)d_in[idx++];

    char* ws = (char*)d_ws;
    size_t off = 0;
    auto walloc = [&](size_t bytes) -> float* {
        float* p = (float*)(ws + off);
        off += (bytes + 255) & ~(size_t)255;
        return p;
    };
    const size_t STATE = (size_t)Hf * 64 * sizeof(float); // 128 KiB
    float* xT0 = walloc((size_t)Tt * INF * 64 * sizeof(float)); // 33.5 MB, [t][k][b]
    float* y0  = walloc((size_t)Tt * Hf * 64 * sizeof(float));  // 67 MB,  [t][c][b]
    KParams P;
    P.xT0 = xT0; P.y0 = y0;
    P.Win0 = W[0][0]; P.Wres0 = W[0][1]; P.Wz0 = W[0][2]; P.bz0 = W[0][3];
    P.Wr0 = W[0][4]; P.br0 = W[0][5]; P.Wc0 = W[0][6]; P.bc0 = W[0][7];
    P.Wg0 = W[0][8]; P.bg0 = W[0][9]; P.Wp0 = W[0][10]; P.bp0 = W[0][11];
    P.Win1 = W[1][0]; P.Wres1 = W[1][1]; P.Wz1 = W[1][2]; P.bz1 = W[1][3];
    P.Wr1 = W[1][4]; P.br1 = W[1][5]; P.Wc1 = W[1][6]; P.bc1 = W[1][7];
    P.Wg1 = W[1][8]; P.bg1 = W[1][9]; P.Wp1 = W[1][10]; P.bp1 = W[1][11];
    P.r00 = walloc(STATE); P.r01 = walloc(STATE);
    P.h00 = walloc(STATE); P.h01 = walloc(STATE);
    P.rh0 = walloc(STATE); P.hg0 = walloc(STATE);
    P.r10 = walloc(STATE); P.r11 = walloc(STATE);
    P.h10 = walloc(STATE); P.h11 = walloc(STATE);
    P.rh1 = walloc(STATE); P.hg1 = walloc(STATE);
    float* hidT = walloc(STATE);
    P.ctr = (unsigned*)walloc(256);   // single barrier counter (own line)
    (void)ws_size;

    hipFuncSetAttribute((const void*)esn_dual_k,
                        hipFuncAttributeMaxDynamicSharedMemorySize, SMEM_BYTES);

    transpose_x_k<<<dim3(Tt, INF / 64), 256, 0, stream>>>(x, xT0);

    hipMemsetAsync(P.ctr, 0, 256, stream);
    hipMemsetAsync(P.r00, 0, STATE, stream);
    hipMemsetAsync(P.h00, 0, STATE, stream);
    hipMemsetAsync(P.r10, 0, STATE, stream);
    hipMemsetAsync(P.h10, 0, STATE, stream);

    esn_dual_k<<<NBLK, NTHR, SMEM_BYTES, stream>>>(P);

    // t=511 (odd) wrote buffer 0 -> layer-1 final h is in h10.
    head1_k<<<dim3(32, 1), 256, 0, stream>>>(P.h10, Wo1, bo1, hidT);
    head2_k<<<dim3(1, 1), 640, 0, stream>>>(hidT, Wo2, bo2, (float*)d_out);
}